// Round 12
// baseline (388.027 us; speedup 1.0000x reference)
//
#include <hip/hip_runtime.h>
#include <hip/hip_bf16.h>
#include <stdint.h>

// AFT-full, MI355X. Shapes: x[64,1024,512], W*[512,512], pos_bias[1024,1024].
//   q,k,v = x W^T + b ; out = sigmoid(q) * (eb@(e^k*v)) / (eb@e^k), eb=exp(pos_bias)
// Pipeline:
//   K0: eb = bf16(exp(pos_bias));  K1: xb = bf16(x), Wb = [Wq; Wk/Wv interleaved]
//   P1: fused QKV GEMM -> s (sigmoid(q), natural), Z (ekv/ek K-major interleaved)
//   P2: merged GEMM C[i,n] = eb @ Z^T, register-local num/den division epilogue.
// r12: PERSISTENT blocks (r11 schedule/ledger/layout untouched).
//   k_aft: 256 blocks, each owns one i-tile and loops 4 n-tiles; absolute tile
//   counter 0..63 streams through ONE continuous 8-phase pipeline (B panel
//   switches at t>>4); epilogue is register-only (no LDS) so no drain between
//   n-tiles — prologue/drain paid once instead of 4x.
//   k_qkv: 256 blocks loop the 6 e-tiles (drain per e-tile kept: epilogue uses
//   the LDS overlay), amortizing launches and keeping the xb panel L2-hot.
// 8-phase ledger (iter: T even, U=T+1, bufs by tile parity, vmcnt(4) at ph4/ph8
// only — counted, never 0 in-loop) as derived in r11; WAR sealed by phase
// barriers, RAW by the two counted waits. Paired-row LDS half [256r][32c]
// (0 conflicts, r7-verified): (r,c) at p*64+(r&1)*32+((c>>3)^(p&3))*8, p=r>>1;
// stage pre-swizzles the global source (both-sides rule).
// Workspace: eb 2MiB@0, Wb 1.5MiB@2MiB, xb 64MiB@4MiB, s 64MiB@68MiB, Z 128MiB@132MiB.

#define NSEQ 1024
#define DM   512

typedef __attribute__((ext_vector_type(8))) short bf16x8;
typedef __attribute__((ext_vector_type(4))) float f32x4;

static __device__ __forceinline__ float b2f(unsigned short u) {
    union { uint32_t i; float f; } c; c.i = ((uint32_t)u) << 16; return c.f;
}
static __device__ __forceinline__ unsigned short f2b(float f) {
    union { float f; uint32_t i; } c; c.f = f;
    uint32_t r = c.i + 0x7FFFu + ((c.i >> 16) & 1u);
    return (unsigned short)(r >> 16);
}
static __device__ __forceinline__ void gl_lds16(const unsigned short* g, unsigned short* l) {
    __builtin_amdgcn_global_load_lds(
        (const __attribute__((address_space(1))) unsigned int*)(g),
        (__attribute__((address_space(3))) unsigned int*)(l), 16, 0, 0);
}

#define PH_BAR() do { asm volatile("" ::: "memory"); \
    __builtin_amdgcn_s_barrier(); asm volatile("" ::: "memory"); } while (0)

__global__ void k_eb(const float* __restrict__ pb, unsigned short* __restrict__ eb) {
    int i = blockIdx.x * 256 + threadIdx.x;
    float4 v = reinterpret_cast<const float4*>(pb)[i];
    union { unsigned short u[4]; uint2 p; } o;
    o.u[0] = f2b(__expf(v.x)); o.u[1] = f2b(__expf(v.y));
    o.u[2] = f2b(__expf(v.z)); o.u[3] = f2b(__expf(v.w));
    reinterpret_cast<uint2*>(eb)[i] = o.p;
}

__global__ void k_cvt(const float* __restrict__ src, unsigned short* __restrict__ dst) {
    int i = blockIdx.x * 256 + threadIdx.x;
    const float4* p = reinterpret_cast<const float4*>(src) + (size_t)i * 2;
    float4 f0 = p[0], f1 = p[1];
    union { unsigned short u[8]; int4 v; } o;
    o.u[0]=f2b(f0.x); o.u[1]=f2b(f0.y); o.u[2]=f2b(f0.z); o.u[3]=f2b(f0.w);
    o.u[4]=f2b(f1.x); o.u[5]=f2b(f1.y); o.u[6]=f2b(f1.z); o.u[7]=f2b(f1.w);
    reinterpret_cast<int4*>(dst)[i] = o.v;
}

__global__ void k_cvt_kv(const float* __restrict__ src, unsigned short* __restrict__ Wb,
                         int toff) {
    int i = blockIdx.x * 256 + threadIdx.x;
    int r = i >> 6, c8 = i & 63;
    const float4* p = reinterpret_cast<const float4*>(src + (size_t)r * DM + c8 * 8);
    float4 f0 = p[0], f1 = p[1];
    union { unsigned short u[8]; int4 v; } o;
    o.u[0]=f2b(f0.x); o.u[1]=f2b(f0.y); o.u[2]=f2b(f0.z); o.u[3]=f2b(f0.w);
    o.u[4]=f2b(f1.x); o.u[5]=f2b(f1.y); o.u[6]=f2b(f1.z); o.u[7]=f2b(f1.w);
    int r2 = 512 + ((r >> 6) << 7) + toff + (r & 63);
    *reinterpret_cast<int4*>(&Wb[(size_t)r2 * DM + c8 * 8]) = o.v;
}

// ---------------- shared 8-phase K-loop (BK=64, 2 bufs x 2 K-halves) ---------
// Used by k_qkv. LDS shorts: A half(d,c) @ (d*2+c)*8192 ; B @ 32768 + same.
template<int NT>   // NT = K/64, even
static __device__ __forceinline__ void gemm8(
    const unsigned short* __restrict__ Abase,
    const unsigned short* __restrict__ Bbase,
    int lda, int ldb, unsigned short* smem, f32x4 (&acc)[8][4],
    int wave, int lane)
{
    const int wr = wave >> 2, wq = wave & 3;
    const int lrow = lane & 15, lkg = lane >> 4;
    const int po = lane >> 3, sub = (lane >> 2) & 1, qp = lane & 3;
    const int ch0 = wave * 2;

    auto half = [&](int isB, int d, int c) -> unsigned short* {
        return smem + isB * 32768 + (d * 2 + c) * 8192;
    };
    auto stg = [&](int isB, int d, int c, int t) {
        const unsigned short* gb = isB ? Bbase : Abase;
        const int ld = isB ? ldb : lda;
        unsigned short* dst = half(isB, d, c);
        #pragma unroll
        for (int q2 = 0; q2 < 2; ++q2) {
            int ch = ch0 + q2;
            int p = ch * 8 + po, r = p * 2 + sub;
            int col = ((t & (NT - 1)) << 6) + (c << 5) + ((qp ^ (p & 3)) << 3);
            gl_lds16(gb + (size_t)r * ld + col, dst + ch * 512);
        }
    };
    auto ldA = [&](int d, int c, int h, bf16x8* af) {
        const unsigned short* base = half(0, d, c);
        #pragma unroll
        for (int mi = 0; mi < 4; ++mi) {
            int r = wr * 128 + h * 64 + mi * 16 + lrow, p = r >> 1;
            af[mi] = *reinterpret_cast<const bf16x8*>(
                base + p * 64 + (r & 1) * 32 + ((lkg ^ (p & 3)) << 3));
        }
    };
    auto ldB = [&](int d, int c, bf16x8* bf) {
        const unsigned short* base = half(1, d, c);
        #pragma unroll
        for (int ni = 0; ni < 4; ++ni) {
            int r = wq * 64 + ni * 16 + lrow, p = r >> 1;
            bf[ni] = *reinterpret_cast<const bf16x8*>(
                base + p * 64 + (r & 1) * 32 + ((lkg ^ (p & 3)) << 3));
        }
    };
    auto mm = [&](int h, bf16x8* af, bf16x8* bf) {
        __builtin_amdgcn_s_setprio(1);
        #pragma unroll
        for (int mi = 0; mi < 4; ++mi)
            #pragma unroll
            for (int ni = 0; ni < 4; ++ni)
                acc[h * 4 + mi][ni] = __builtin_amdgcn_mfma_f32_16x16x32_bf16(
                    af[mi], bf[ni], acc[h * 4 + mi][ni], 0, 0, 0);
        __builtin_amdgcn_s_setprio(0);
    };

    stg(0, 0, 0, 0); stg(1, 0, 0, 0);
    stg(0, 0, 1, 0); stg(1, 0, 1, 0);
    stg(0, 1, 0, 1); stg(1, 1, 0, 1);
    asm volatile("s_waitcnt vmcnt(4)" ::: "memory");
    __builtin_amdgcn_s_barrier();
    asm volatile("" ::: "memory");

    #pragma unroll 1
    for (int i = 0; i < NT / 2; ++i) {
        const int U = 2 * i + 1, T2 = 2 * i + 2, U2 = 2 * i + 3;
        bf16x8 af[4], bf[4];
        ldB(0, 0, bf); ldA(0, 0, 0, af); stg(0, 1, 1, U);
        PH_BAR(); mm(0, af, bf); PH_BAR();
        ldA(0, 0, 1, af); stg(1, 1, 1, U);
        PH_BAR(); mm(1, af, bf); PH_BAR();
        ldB(0, 1, bf); ldA(0, 1, 0, af); stg(0, 0, 0, T2);
        PH_BAR(); mm(0, af, bf); PH_BAR();
        ldA(0, 1, 1, af); stg(1, 0, 0, T2);
        asm volatile("s_waitcnt vmcnt(4)" ::: "memory");
        PH_BAR(); mm(1, af, bf); PH_BAR();
        ldB(1, 0, bf); ldA(1, 0, 0, af); stg(0, 0, 1, T2);
        PH_BAR(); mm(0, af, bf); PH_BAR();
        ldA(1, 0, 1, af); stg(1, 0, 1, T2);
        PH_BAR(); mm(1, af, bf); PH_BAR();
        ldB(1, 1, bf); ldA(1, 1, 0, af); stg(0, 1, 0, U2);
        PH_BAR(); mm(0, af, bf); PH_BAR();
        ldA(1, 1, 1, af); stg(1, 1, 0, U2);
        asm volatile("s_waitcnt vmcnt(4)" ::: "memory");
        PH_BAR(); mm(1, af, bf); PH_BAR();
    }
    asm volatile("s_waitcnt vmcnt(0)" ::: "memory");   // drain garbage tail
    __builtin_amdgcn_s_barrier();
    asm volatile("" ::: "memory");
}

// ---------------- P1: fused QKV projection (persistent over e-tiles) --------
// 256 blocks = 256 mtiles; each loops etile 0..5. xb panel stays L2-hot.
__launch_bounds__(512)
__global__ void k_qkv(const unsigned short* __restrict__ xb,
                      const unsigned short* __restrict__ Wb,
                      const float* __restrict__ bq, const float* __restrict__ bk,
                      const float* __restrict__ bv,
                      unsigned short* __restrict__ s_out,
                      unsigned short* __restrict__ Z)
{
    extern __shared__ unsigned short smem[];          // 131072 B
    const int bid = blockIdx.x;
    const int mtile = (bid & 7) * 32 + (bid >> 3);    // bijective: 256 % 8 == 0
    const int brow = mtile * 256;

    const int tid = threadIdx.x;
    const int lane = tid & 63, wave = tid >> 6;
    const int wr = wave >> 2, wq = wave & 3;
    const int lrow = lane & 15, lkg = lane >> 4;

    const f32x4 z4 = {0.f, 0.f, 0.f, 0.f};
    f32x4 acc[8][4];

    #pragma unroll 1
    for (int etile = 0; etile < 6; ++etile) {
        __syncthreads();                              // seal prev T-overlay reads
        #pragma unroll
        for (int a = 0; a < 8; ++a)
            #pragma unroll
            for (int c = 0; c < 4; ++c) acc[a][c] = z4;

        gemm8<8>(xb + (size_t)brow * DM, Wb + (size_t)etile * 256 * DM, DM, DM,
                 smem, acc, wave, lane);

        const bool isq = (etile < 2);
        unsigned short* T = smem;                      // [*][136] overlay
        if (isq) {
            const int ecol = etile * 256;
            #pragma unroll
            for (int pp = 0; pp < 2; ++pp) {
                __syncthreads();
                if ((wq >> 1) == pp) {
                    #pragma unroll
                    for (int mi = 0; mi < 8; ++mi) {
                        int m0 = wr*128 + mi*16 + lkg*4;
                        #pragma unroll
                        for (int ni = 0; ni < 4; ++ni) {
                            int nl = (wq & 1) * 64 + ni*16 + lrow;
                            float bia = bq[ecol + pp*128 + nl];
                            #pragma unroll
                            for (int r = 0; r < 4; ++r) {
                                float tq = acc[mi][ni][r] + bia;
                                float sg = __builtin_amdgcn_rcpf(1.f + __expf(-tq));
                                T[(m0 + r) * 136 + nl] = f2b(sg);
                            }
                        }
                    }
                }
                __syncthreads();
                #pragma unroll
                for (int it = 0; it < 8; ++it) {
                    int idx = it * 512 + tid;
                    int m = idx >> 4, ng = idx & 15;
                    int4 vv = *reinterpret_cast<const int4*>(&T[m * 136 + ng * 8]);
                    *reinterpret_cast<int4*>(
                        &s_out[(size_t)(brow + m) * DM + ecol + pp*128 + ng * 8]) = vv;
                }
            }
        } else {
            const int gbase = (etile - 2) * 2;
            const int b = brow >> 10;
            #pragma unroll
            for (int pp = 0; pp < 2; ++pp) {          // m-half
                __syncthreads();
                if (wr == pp) {
                    #pragma unroll
                    for (int mi = 0; mi < 8; ++mi) {
                        int m0 = mi*16 + lkg*4;
                        #pragma unroll
                        for (int ni = 0; ni < 4; ++ni) {
                            int n = wq*64 + ni*16 + lrow;
                            int sub = (n >> 6) & 1, dr = n & 63;
                            int d = (gbase + (n >> 7)) * 64 + dr;
                            float bia = (sub == 0) ? bk[d] : bv[d];
                            union { unsigned short u[4]; uint2 p; } o;
                            #pragma unroll
                            for (int r = 0; r < 4; ++r) {
                                float tv = acc[mi][ni][r] + bia;
                                o.u[r] = f2b((sub == 0) ? __expf(tv) : tv);
                            }
                            *reinterpret_cast<uint2*>(&T[n * 136 + m0]) = o.p;
                        }
                    }
                }
                __syncthreads();
                const int j0 = (brow & (NSEQ - 1)) + pp * 128;
                #pragma unroll
                for (int it = 0; it < 8; ++it) {
                    int idx = it * 512 + tid;
                    int zr = idx >> 4, jg = idx & 15;
                    int gg = zr >> 7, sub2 = (zr >> 6) & 1, dr = zr & 63;
                    int d = (gbase + gg) * 64 + dr;
                    union { unsigned short u[8]; int4 v; } o;
                    if (sub2 == 0) {
                        union { unsigned short u[8]; int4 v; } pe, pv;
                        pe.v = *reinterpret_cast<const int4*>(&T[(gg*128 + dr) * 136 + jg*8]);
                        pv.v = *reinterpret_cast<const int4*>(&T[(gg*128 + 64 + dr) * 136 + jg*8]);
                        #pragma unroll
                        for (int j = 0; j < 8; ++j) o.u[j] = f2b(b2f(pe.u[j]) * b2f(pv.u[j]));
                    } else {
                        o.v = *reinterpret_cast<const int4*>(&T[(gg*128 + dr) * 136 + jg*8]);
                    }
                    int nn = ((d >> 4) << 5) + sub2 * 16 + (d & 15);
                    size_t off = ((size_t)(b * NSEQ + nn)) * NSEQ + j0 + jg * 8;
                    *reinterpret_cast<int4*>(&Z[off]) = o.v;
                }
            }
        }
    }
}

// ---------------- P2: merged mixing GEMM (persistent, continuous pipeline) ---
// 256 blocks = 4 itiles x 64 ncols; each block streams 4 n-tiles (64 K-tiles)
// through ONE pipeline; epilogue is register-only (no LDS) -> no drain between.
__launch_bounds__(512)
__global__ void k_aft(const unsigned short* __restrict__ eb,
                      const unsigned short* __restrict__ Z,
                      const unsigned short* __restrict__ s_in,
                      float* __restrict__ out)
{
    extern __shared__ unsigned short smem[];          // 131072 B
    const int bid = blockIdx.x;
    const int logical = (bid & 7) * 32 + (bid >> 3);  // bijective: 256 % 8 == 0
    const int itile = logical & 3, ncol = logical >> 2;
    const int i0 = itile * 256;

    const int tid = threadIdx.x;
    const int lane = tid & 63, wave = tid >> 6;
    const int wr = wave >> 2, wq = wave & 3;
    const int lrow = lane & 15, lkg = lane >> 4;
    const int po = lane >> 3, sub = (lane >> 2) & 1, qp = lane & 3;
    const int ch0 = wave * 2;

    const unsigned short* Abase = eb + (size_t)i0 * NSEQ;
    const unsigned short* Bbase = Z + (size_t)ncol * 4 * 256 * NSEQ;

    f32x4 acc[8][4];
    const f32x4 z4 = {0.f, 0.f, 0.f, 0.f};
    #pragma unroll
    for (int a = 0; a < 8; ++a)
        #pragma unroll
        for (int c = 0; c < 4; ++c) acc[a][c] = z4;

    auto half = [&](int isB, int d, int c) -> unsigned short* {
        return smem + isB * 32768 + (d * 2 + c) * 8192;
    };
    auto stg = [&](int isB, int d, int c, int t) {
        int ta = t & 63, gp = ta >> 4, tk = ta & 15;   // panel, K-tile within
        unsigned short* dst = half(isB, d, c);
        #pragma unroll
        for (int q2 = 0; q2 < 2; ++q2) {
            int ch = ch0 + q2;
            int p = ch * 8 + po, r = p * 2 + sub;
            int col = (tk << 6) + (c << 5) + ((qp ^ (p & 3)) << 3);
            const unsigned short* g = isB
                ? Bbase + ((size_t)(gp * 256 + r)) * NSEQ + col
                : Abase + (size_t)r * NSEQ + col;
            gl_lds16(g, dst + ch * 512);
        }
    };
    auto ldA = [&](int d, int c, int h, bf16x8* af) {
        const unsigned short* base = half(0, d, c);
        #pragma unroll
        for (int mi = 0; mi < 4; ++mi) {
            int r = wr * 128 + h * 64 + mi * 16 + lrow, p = r >> 1;
            af[mi] = *reinterpret_cast<const bf16x8*>(
                base + p * 64 + (r & 1) * 32 + ((lkg ^ (p & 3)) << 3));
        }
    };
    auto ldB = [&](int d, int c, bf16x8* bf) {
        const unsigned short* base = half(1, d, c);
        #pragma unroll
        for (int ni = 0; ni < 4; ++ni) {
            int r = wq * 64 + ni * 16 + lrow, p = r >> 1;
            bf[ni] = *reinterpret_cast<const bf16x8*>(
                base + p * 64 + (r & 1) * 32 + ((lkg ^ (p & 3)) << 3));
        }
    };
    auto mm = [&](int h, bf16x8* af, bf16x8* bf) {
        __builtin_amdgcn_s_setprio(1);
        #pragma unroll
        for (int mi = 0; mi < 4; ++mi)
            #pragma unroll
            for (int ni = 0; ni < 4; ++ni)
                acc[h * 4 + mi][ni] = __builtin_amdgcn_mfma_f32_16x16x32_bf16(
                    af[mi], bf[ni], acc[h * 4 + mi][ni], 0, 0, 0);
        __builtin_amdgcn_s_setprio(0);
    };

    // prologue: t0 k0, t0 k1, t1 k0; vmcnt(4) forces all of t0
    stg(0, 0, 0, 0); stg(1, 0, 0, 0);
    stg(0, 0, 1, 0); stg(1, 0, 1, 0);
    stg(0, 1, 0, 1); stg(1, 1, 0, 1);
    asm volatile("s_waitcnt vmcnt(4)" ::: "memory");
    __builtin_amdgcn_s_barrier();
    asm volatile("" ::: "memory");

    #pragma unroll 1
    for (int g = 0; g < 4; ++g) {
        #pragma unroll 1
        for (int ii = 0; ii < 8; ++ii) {
            const int T = (g << 4) + (ii << 1);
            const int U = T + 1, T2 = T + 2, U2 = T + 3;
            bf16x8 af[4], bf[4];
            ldB(0, 0, bf); ldA(0, 0, 0, af); stg(0, 1, 1, U);
            PH_BAR(); mm(0, af, bf); PH_BAR();
            ldA(0, 0, 1, af); stg(1, 1, 1, U);
            PH_BAR(); mm(1, af, bf); PH_BAR();
            ldB(0, 1, bf); ldA(0, 1, 0, af); stg(0, 0, 0, T2);
            PH_BAR(); mm(0, af, bf); PH_BAR();
            ldA(0, 1, 1, af); stg(1, 0, 0, T2);
            asm volatile("s_waitcnt vmcnt(4)" ::: "memory");
            PH_BAR(); mm(1, af, bf); PH_BAR();
            ldB(1, 0, bf); ldA(1, 0, 0, af); stg(0, 0, 1, T2);
            PH_BAR(); mm(0, af, bf); PH_BAR();
            ldA(1, 0, 1, af); stg(1, 0, 1, T2);
            PH_BAR(); mm(1, af, bf); PH_BAR();
            ldB(1, 1, bf); ldA(1, 1, 0, af); stg(0, 1, 0, U2);
            PH_BAR(); mm(0, af, bf); PH_BAR();
            ldA(1, 1, 1, af); stg(1, 1, 0, U2);
            asm volatile("s_waitcnt vmcnt(4)" ::: "memory");
            PH_BAR(); mm(1, af, bf); PH_BAR();
        }
        // register-only epilogue for n-tile g (no LDS, no drain); re-zero acc.
        const int n0 = (ncol * 4 + g) * 256;
        #pragma unroll
        for (int mi = 0; mi < 8; ++mi) {
            int i = i0 + wr*128 + mi*16 + lkg*4;
            #pragma unroll
            for (int pi = 0; pi < 2; ++pi) {
                int nA = n0 + wq*64 + pi*32 + lrow;
                int b  = nA >> 10, nn = nA & (NSEQ - 1);
                int d  = ((nn >> 5) << 4) + (nn & 15);
                #pragma unroll
                for (int r = 0; r < 4; ++r) {
                    size_t o = ((size_t)(b * NSEQ + i + r)) * DM + d;
                    out[o] = b2f(s_in[o]) * acc[mi][pi*2][r] / acc[mi][pi*2 + 1][r];
                }
                acc[mi][pi*2] = z4; acc[mi][pi*2 + 1] = z4;
            }
        }
    }
    asm volatile("s_waitcnt vmcnt(0)" ::: "memory");   // drain wrapped tail
}

extern "C" void kernel_launch(void* const* d_in, const int* in_sizes, int n_in,
                              void* d_out, int out_size, void* d_ws, size_t ws_size,
                              hipStream_t stream)
{
    const float* x  = (const float*)d_in[0];
    const float* Wq = (const float*)d_in[1];
    const float* bq = (const float*)d_in[2];
    const float* Wk = (const float*)d_in[3];
    const float* bk = (const float*)d_in[4];
    const float* Wv = (const float*)d_in[5];
    const float* bv = (const float*)d_in[6];
    const float* pb = (const float*)d_in[7];
    float* out = (float*)d_out;

    char* ws = (char*)d_ws;
    unsigned short* eb  = (unsigned short*)(ws);                          // 2 MiB
    unsigned short* Wb  = (unsigned short*)(ws + ((size_t)2   << 20));    // 1.5 MiB
    unsigned short* xb  = (unsigned short*)(ws + ((size_t)4   << 20));    // 64 MiB
    unsigned short* s   = (unsigned short*)(ws + ((size_t)68  << 20));    // 64 MiB
    unsigned short* Z   = (unsigned short*)(ws + ((size_t)132 << 20));    // 128 MiB

    k_eb <<<1024, 256, 0, stream>>>(pb, eb);
    k_cvt<<<16384, 256, 0, stream>>>(x,  xb);
    k_cvt<<<128,   256, 0, stream>>>(Wq, Wb);
    k_cvt_kv<<<128, 256, 0, stream>>>(Wk, Wb, 0);
    k_cvt_kv<<<128, 256, 0, stream>>>(Wv, Wb, 64);
    k_qkv<<<256, 512, 131072, stream>>>(xb, Wb, bq, bk, bv, s, Z);
    k_aft<<<256, 512, 131072, stream>>>(eb, Z, s, out);
}

// Round 13
// 335.244 us; speedup vs baseline: 1.1574x; 1.1574x over previous
//
#include <hip/hip_runtime.h>
#include <hip/hip_bf16.h>
#include <stdint.h>

// AFT-full, MI355X. Shapes: x[64,1024,512], W*[512,512], pos_bias[1024,1024].
//   q,k,v = x W^T + b ; out = sigmoid(q) * (eb@(e^k*v)) / (eb@e^k), eb=exp(pos_bias)
// Pipeline:
//   K0: eb = bf16(exp(pos_bias));  K1: xb = bf16(x), Wb = [Wq; Wk/Wv interleaved]
//   P1: fused QKV GEMM -> s (sigmoid(q), natural), Z (ekv/ek K-major interleaved)
//   P2: merged GEMM C[i,n] = eb @ Z^T, register-local num/den division epilogue.
// r13 = best-of-both recombination:
//   k_qkv: r8's version (1536 blocks, gemm_p: BK=32, 4 LDS slots, depth-3
//   prefetch, ONE vmcnt(8)+barrier per tile). Concurrent etile-blocks share the
//   xb panel in L2 (FETCH ~44 MB) — persistence thrashed it (r12: 275 MB).
//   k_aft: r12's persistent version (256 blocks, 8-phase BK=64 counted-vmcnt
//   pipeline, 4 n-tiles streamed with NO drain — register-only epilogue).
// Paired-row LDS layout everywhere (0 conflicts, r7-verified): (r,c) at
// p*64+(r&1)*32+((c>>3)^(p&3))*8 shorts, p=r>>1; stage pre-swizzles global src.
// Workspace: eb 2MiB@0, Wb 1.5MiB@2MiB, xb 64MiB@4MiB, s 64MiB@68MiB, Z 128MiB@132MiB.

#define NSEQ 1024
#define DM   512

typedef __attribute__((ext_vector_type(8))) short bf16x8;
typedef __attribute__((ext_vector_type(4))) float f32x4;

static __device__ __forceinline__ float b2f(unsigned short u) {
    union { uint32_t i; float f; } c; c.i = ((uint32_t)u) << 16; return c.f;
}
static __device__ __forceinline__ unsigned short f2b(float f) {
    union { float f; uint32_t i; } c; c.f = f;
    uint32_t r = c.i + 0x7FFFu + ((c.i >> 16) & 1u);
    return (unsigned short)(r >> 16);
}
static __device__ __forceinline__ void gl_lds16(const unsigned short* g, unsigned short* l) {
    __builtin_amdgcn_global_load_lds(
        (const __attribute__((address_space(1))) unsigned int*)(g),
        (__attribute__((address_space(3))) unsigned int*)(l), 16, 0, 0);
}

#define PH_BAR() do { asm volatile("" ::: "memory"); \
    __builtin_amdgcn_s_barrier(); asm volatile("" ::: "memory"); } while (0)

__global__ void k_eb(const float* __restrict__ pb, unsigned short* __restrict__ eb) {
    int i = blockIdx.x * 256 + threadIdx.x;
    float4 v = reinterpret_cast<const float4*>(pb)[i];
    union { unsigned short u[4]; uint2 p; } o;
    o.u[0] = f2b(__expf(v.x)); o.u[1] = f2b(__expf(v.y));
    o.u[2] = f2b(__expf(v.z)); o.u[3] = f2b(__expf(v.w));
    reinterpret_cast<uint2*>(eb)[i] = o.p;
}

__global__ void k_cvt(const float* __restrict__ src, unsigned short* __restrict__ dst) {
    int i = blockIdx.x * 256 + threadIdx.x;
    const float4* p = reinterpret_cast<const float4*>(src) + (size_t)i * 2;
    float4 f0 = p[0], f1 = p[1];
    union { unsigned short u[8]; int4 v; } o;
    o.u[0]=f2b(f0.x); o.u[1]=f2b(f0.y); o.u[2]=f2b(f0.z); o.u[3]=f2b(f0.w);
    o.u[4]=f2b(f1.x); o.u[5]=f2b(f1.y); o.u[6]=f2b(f1.z); o.u[7]=f2b(f1.w);
    reinterpret_cast<int4*>(dst)[i] = o.v;
}

__global__ void k_cvt_kv(const float* __restrict__ src, unsigned short* __restrict__ Wb,
                         int toff) {
    int i = blockIdx.x * 256 + threadIdx.x;
    int r = i >> 6, c8 = i & 63;
    const float4* p = reinterpret_cast<const float4*>(src + (size_t)r * DM + c8 * 8);
    float4 f0 = p[0], f1 = p[1];
    union { unsigned short u[8]; int4 v; } o;
    o.u[0]=f2b(f0.x); o.u[1]=f2b(f0.y); o.u[2]=f2b(f0.z); o.u[3]=f2b(f0.w);
    o.u[4]=f2b(f1.x); o.u[5]=f2b(f1.y); o.u[6]=f2b(f1.z); o.u[7]=f2b(f1.w);
    int r2 = 512 + ((r >> 6) << 7) + toff + (r & 63);
    *reinterpret_cast<int4*>(&Wb[(size_t)r2 * DM + c8 * 8]) = o.v;
}

// ------ r8 K-loop for k_qkv (BK=32, 4 slots, depth-3, 1 barrier/tile) --------
// LDS shorts: A slot s @ s*8192 ; B slot s @ 32768 + s*8192. NT = K/32 (mult 4).
template<int NT>
static __device__ __forceinline__ void gemm_p(
    const unsigned short* __restrict__ Abase,
    const unsigned short* __restrict__ Bbase,
    int lda, int ldb, unsigned short* smem, f32x4 (&acc)[8][4],
    int wave, int lane)
{
    const int wr = wave >> 2, wq = wave & 3;
    const int lrow = lane & 15, lkg = lane >> 4;
    const int po  = lane >> 3;
    const int sub = (lane >> 2) & 1;
    const int qp  = lane & 3;

    auto stage = [&](int mat, int s, int h, int t) {
        int p = h * 64 + wave * 8 + po;
        int r = p * 2 + sub;
        int q = qp ^ (p & 3);
        int col = ((t & (NT - 1)) << 5) + q * 8;
        const unsigned short* g = (mat ? Bbase + (size_t)r * ldb
                                       : Abase + (size_t)r * lda) + col;
        unsigned short* d = smem + mat * 32768 + s * 8192 + (h * 64 + wave * 8) * 64;
        gl_lds16(g, d);
    };
    auto loadA = [&](int s, int h, bf16x8* af) {
        const unsigned short* base = smem + s * 8192;
        #pragma unroll
        for (int mi = 0; mi < 4; ++mi) {
            int r = wr * 128 + h * 64 + mi * 16 + lrow;
            int p = r >> 1;
            af[mi] = *reinterpret_cast<const bf16x8*>(
                base + p * 64 + (r & 1) * 32 + ((lkg ^ (p & 3)) << 3));
        }
    };
    auto loadB = [&](int s, bf16x8* bf) {
        const unsigned short* base = smem + 32768 + s * 8192;
        #pragma unroll
        for (int ni = 0; ni < 4; ++ni) {
            int r = wq * 64 + ni * 16 + lrow;
            int p = r >> 1;
            bf[ni] = *reinterpret_cast<const bf16x8*>(
                base + p * 64 + (r & 1) * 32 + ((lkg ^ (p & 3)) << 3));
        }
    };
    auto mfma16 = [&](int h, bf16x8* af, bf16x8* bf) {
        __builtin_amdgcn_s_setprio(1);
        #pragma unroll
        for (int mi = 0; mi < 4; ++mi)
            #pragma unroll
            for (int ni = 0; ni < 4; ++ni)
                acc[h * 4 + mi][ni] = __builtin_amdgcn_mfma_f32_16x16x32_bf16(
                    af[mi], bf[ni], acc[h * 4 + mi][ni], 0, 0, 0);
        __builtin_amdgcn_s_setprio(0);
    };

    #pragma unroll
    for (int pt = 0; pt < 3; ++pt) {
        stage(0, pt, 0, pt); stage(0, pt, 1, pt);
        stage(1, pt, 0, pt); stage(1, pt, 1, pt);
    }
    asm volatile("s_waitcnt vmcnt(8)" ::: "memory");
    __builtin_amdgcn_s_barrier();

    #pragma unroll 1
    for (int tt = 0; tt < NT; tt += 4) {
        #pragma unroll
        for (int u = 0; u < 4; ++u) {
            const int t = tt + u;
            const int s = u, s3 = (u + 3) & 3, t3 = t + 3;
            bf16x8 af[4], bfr[4];
            loadB(s, bfr); loadA(s, 0, af);
            stage(0, s3, 0, t3); stage(0, s3, 1, t3);
            mfma16(0, af, bfr);
            loadA(s, 1, af);
            stage(1, s3, 0, t3); stage(1, s3, 1, t3);
            mfma16(1, af, bfr);
            asm volatile("s_waitcnt vmcnt(8)" ::: "memory");
            __builtin_amdgcn_s_barrier();
        }
    }
    asm volatile("s_waitcnt vmcnt(0)" ::: "memory");   // drain garbage tail
    __builtin_amdgcn_s_barrier();
}

// ---------------- P1: fused QKV projection (r8 version) ----------------
// 1536 blocks = 256 mtiles x 6 etiles; XCD-chunked, etile fastest.
__launch_bounds__(512)
__global__ void k_qkv(const unsigned short* __restrict__ xb,
                      const unsigned short* __restrict__ Wb,
                      const float* __restrict__ bq, const float* __restrict__ bk,
                      const float* __restrict__ bv,
                      unsigned short* __restrict__ s_out,
                      unsigned short* __restrict__ Z)
{
    extern __shared__ unsigned short smem[];          // 131072 B
    const int bid = blockIdx.x;
    const int logical = (bid & 7) * 192 + (bid >> 3);
    const int mtile = logical / 6, etile = logical % 6;
    const int brow = mtile * 256;
    const int erow = etile * 256;
    const bool isq = (etile < 2);

    const int tid = threadIdx.x;
    const int lane = tid & 63, wave = tid >> 6;
    const int wr = wave >> 2, wq = wave & 3;
    const int lrow = lane & 15, lkg = lane >> 4;

    f32x4 acc[8][4];
    const f32x4 z4 = {0.f, 0.f, 0.f, 0.f};
    #pragma unroll
    for (int a = 0; a < 8; ++a)
        #pragma unroll
        for (int c = 0; c < 4; ++c) acc[a][c] = z4;

    gemm_p<16>(xb + (size_t)brow * DM, Wb + (size_t)erow * DM, DM, DM,
               smem, acc, wave, lane);

    unsigned short* T = smem;                          // [*][136] overlay
    if (isq) {
        const int ecol = etile * 256;
        #pragma unroll
        for (int pp = 0; pp < 2; ++pp) {
            __syncthreads();
            if ((wq >> 1) == pp) {
                #pragma unroll
                for (int mi = 0; mi < 8; ++mi) {
                    int m0 = wr*128 + mi*16 + lkg*4;
                    #pragma unroll
                    for (int ni = 0; ni < 4; ++ni) {
                        int nl = (wq & 1) * 64 + ni*16 + lrow;
                        float bia = bq[ecol + pp*128 + nl];
                        #pragma unroll
                        for (int r = 0; r < 4; ++r) {
                            float tq = acc[mi][ni][r] + bia;
                            float sg = __builtin_amdgcn_rcpf(1.f + __expf(-tq));
                            T[(m0 + r) * 136 + nl] = f2b(sg);
                        }
                    }
                }
            }
            __syncthreads();
            #pragma unroll
            for (int it = 0; it < 8; ++it) {
                int idx = it * 512 + tid;
                int m = idx >> 4, ng = idx & 15;
                int4 vv = *reinterpret_cast<const int4*>(&T[m * 136 + ng * 8]);
                *reinterpret_cast<int4*>(
                    &s_out[(size_t)(brow + m) * DM + ecol + pp*128 + ng * 8]) = vv;
            }
        }
    } else {
        const int gbase = (etile - 2) * 2;
        const int b = brow >> 10;
        #pragma unroll
        for (int pp = 0; pp < 2; ++pp) {              // m-half
            __syncthreads();
            if (wr == pp) {
                #pragma unroll
                for (int mi = 0; mi < 8; ++mi) {
                    int m0 = mi*16 + lkg*4;
                    #pragma unroll
                    for (int ni = 0; ni < 4; ++ni) {
                        int n = wq*64 + ni*16 + lrow;
                        int sub = (n >> 6) & 1, dr = n & 63;
                        int d = (gbase + (n >> 7)) * 64 + dr;
                        float bia = (sub == 0) ? bk[d] : bv[d];
                        union { unsigned short u[4]; uint2 p; } o;
                        #pragma unroll
                        for (int r = 0; r < 4; ++r) {
                            float tv = acc[mi][ni][r] + bia;
                            o.u[r] = f2b((sub == 0) ? __expf(tv) : tv);
                        }
                        *reinterpret_cast<uint2*>(&T[n * 136 + m0]) = o.p;
                    }
                }
            }
            __syncthreads();
            const int j0 = (brow & (NSEQ - 1)) + pp * 128;
            #pragma unroll
            for (int it = 0; it < 8; ++it) {
                int idx = it * 512 + tid;
                int zr = idx >> 4, jg = idx & 15;
                int gg = zr >> 7, sub2 = (zr >> 6) & 1, dr = zr & 63;
                int d = (gbase + gg) * 64 + dr;
                union { unsigned short u[8]; int4 v; } o;
                if (sub2 == 0) {
                    union { unsigned short u[8]; int4 v; } pe, pv;
                    pe.v = *reinterpret_cast<const int4*>(&T[(gg*128 + dr) * 136 + jg*8]);
                    pv.v = *reinterpret_cast<const int4*>(&T[(gg*128 + 64 + dr) * 136 + jg*8]);
                    #pragma unroll
                    for (int j = 0; j < 8; ++j) o.u[j] = f2b(b2f(pe.u[j]) * b2f(pv.u[j]));
                } else {
                    o.v = *reinterpret_cast<const int4*>(&T[(gg*128 + dr) * 136 + jg*8]);
                }
                int nn = ((d >> 4) << 5) + sub2 * 16 + (d & 15);
                size_t off = ((size_t)(b * NSEQ + nn)) * NSEQ + j0 + jg * 8;
                *reinterpret_cast<int4*>(&Z[off]) = o.v;
            }
        }
    }
}

// ------ P2: persistent merged mixing GEMM (r12 version) ----------------------
// 256 blocks = 4 itiles x 64 ncols; each block streams 4 n-tiles (64 K-tiles)
// through ONE 8-phase pipeline; epilogue register-only -> no drain between.
__launch_bounds__(512)
__global__ void k_aft(const unsigned short* __restrict__ eb,
                      const unsigned short* __restrict__ Z,
                      const unsigned short* __restrict__ s_in,
                      float* __restrict__ out)
{
    extern __shared__ unsigned short smem[];          // 131072 B
    const int bid = blockIdx.x;
    const int logical = (bid & 7) * 32 + (bid >> 3);  // bijective: 256 % 8 == 0
    const int itile = logical & 3, ncol = logical >> 2;
    const int i0 = itile * 256;

    const int tid = threadIdx.x;
    const int lane = tid & 63, wave = tid >> 6;
    const int wr = wave >> 2, wq = wave & 3;
    const int lrow = lane & 15, lkg = lane >> 4;
    const int po = lane >> 3, sub = (lane >> 2) & 1, qp = lane & 3;
    const int ch0 = wave * 2;

    const unsigned short* Abase = eb + (size_t)i0 * NSEQ;
    const unsigned short* Bbase = Z + (size_t)ncol * 4 * 256 * NSEQ;

    f32x4 acc[8][4];
    const f32x4 z4 = {0.f, 0.f, 0.f, 0.f};
    #pragma unroll
    for (int a = 0; a < 8; ++a)
        #pragma unroll
        for (int c = 0; c < 4; ++c) acc[a][c] = z4;

    auto half = [&](int isB, int d, int c) -> unsigned short* {
        return smem + isB * 32768 + (d * 2 + c) * 8192;
    };
    auto stg = [&](int isB, int d, int c, int t) {
        int ta = t & 63, gp = ta >> 4, tk = ta & 15;
        unsigned short* dst = half(isB, d, c);
        #pragma unroll
        for (int q2 = 0; q2 < 2; ++q2) {
            int ch = ch0 + q2;
            int p = ch * 8 + po, r = p * 2 + sub;
            int col = (tk << 6) + (c << 5) + ((qp ^ (p & 3)) << 3);
            const unsigned short* g = isB
                ? Bbase + ((size_t)(gp * 256 + r)) * NSEQ + col
                : Abase + (size_t)r * NSEQ + col;
            gl_lds16(g, dst + ch * 512);
        }
    };
    auto ldA = [&](int d, int c, int h, bf16x8* af) {
        const unsigned short* base = half(0, d, c);
        #pragma unroll
        for (int mi = 0; mi < 4; ++mi) {
            int r = wr * 128 + h * 64 + mi * 16 + lrow, p = r >> 1;
            af[mi] = *reinterpret_cast<const bf16x8*>(
                base + p * 64 + (r & 1) * 32 + ((lkg ^ (p & 3)) << 3));
        }
    };
    auto ldB = [&](int d, int c, bf16x8* bf) {
        const unsigned short* base = half(1, d, c);
        #pragma unroll
        for (int ni = 0; ni < 4; ++ni) {
            int r = wq * 64 + ni * 16 + lrow, p = r >> 1;
            bf[ni] = *reinterpret_cast<const bf16x8*>(
                base + p * 64 + (r & 1) * 32 + ((lkg ^ (p & 3)) << 3));
        }
    };
    auto mm = [&](int h, bf16x8* af, bf16x8* bf) {
        __builtin_amdgcn_s_setprio(1);
        #pragma unroll
        for (int mi = 0; mi < 4; ++mi)
            #pragma unroll
            for (int ni = 0; ni < 4; ++ni)
                acc[h * 4 + mi][ni] = __builtin_amdgcn_mfma_f32_16x16x32_bf16(
                    af[mi], bf[ni], acc[h * 4 + mi][ni], 0, 0, 0);
        __builtin_amdgcn_s_setprio(0);
    };

    stg(0, 0, 0, 0); stg(1, 0, 0, 0);
    stg(0, 0, 1, 0); stg(1, 0, 1, 0);
    stg(0, 1, 0, 1); stg(1, 1, 0, 1);
    asm volatile("s_waitcnt vmcnt(4)" ::: "memory");
    __builtin_amdgcn_s_barrier();
    asm volatile("" ::: "memory");

    #pragma unroll 1
    for (int g = 0; g < 4; ++g) {
        #pragma unroll 1
        for (int ii = 0; ii < 8; ++ii) {
            const int T = (g << 4) + (ii << 1);
            const int U = T + 1, T2 = T + 2, U2 = T + 3;
            bf16x8 af[4], bf[4];
            ldB(0, 0, bf); ldA(0, 0, 0, af); stg(0, 1, 1, U);
            PH_BAR(); mm(0, af, bf); PH_BAR();
            ldA(0, 0, 1, af); stg(1, 1, 1, U);
            PH_BAR(); mm(1, af, bf); PH_BAR();
            ldB(0, 1, bf); ldA(0, 1, 0, af); stg(0, 0, 0, T2);
            PH_BAR(); mm(0, af, bf); PH_BAR();
            ldA(0, 1, 1, af); stg(1, 0, 0, T2);
            asm volatile("s_waitcnt vmcnt(4)" ::: "memory");
            PH_BAR(); mm(1, af, bf); PH_BAR();
            ldB(1, 0, bf); ldA(1, 0, 0, af); stg(0, 0, 1, T2);
            PH_BAR(); mm(0, af, bf); PH_BAR();
            ldA(1, 0, 1, af); stg(1, 0, 1, T2);
            PH_BAR(); mm(1, af, bf); PH_BAR();
            ldB(1, 1, bf); ldA(1, 1, 0, af); stg(0, 1, 0, U2);
            PH_BAR(); mm(0, af, bf); PH_BAR();
            ldA(1, 1, 1, af); stg(1, 1, 0, U2);
            asm volatile("s_waitcnt vmcnt(4)" ::: "memory");
            PH_BAR(); mm(1, af, bf); PH_BAR();
        }
        // register-only epilogue for n-tile g (no LDS, no drain); re-zero acc.
        const int n0 = (ncol * 4 + g) * 256;
        #pragma unroll
        for (int mi = 0; mi < 8; ++mi) {
            int i = i0 + wr*128 + mi*16 + lkg*4;
            #pragma unroll
            for (int pi = 0; pi < 2; ++pi) {
                int nA = n0 + wq*64 + pi*32 + lrow;
                int b  = nA >> 10, nn = nA & (NSEQ - 1);
                int d  = ((nn >> 5) << 4) + (nn & 15);
                #pragma unroll
                for (int r = 0; r < 4; ++r) {
                    size_t o = ((size_t)(b * NSEQ + i + r)) * DM + d;
                    out[o] = b2f(s_in[o]) * acc[mi][pi*2][r] / acc[mi][pi*2 + 1][r];
                }
                acc[mi][pi*2] = z4; acc[mi][pi*2 + 1] = z4;
            }
        }
    }
    asm volatile("s_waitcnt vmcnt(0)" ::: "memory");   // drain wrapped tail
}

extern "C" void kernel_launch(void* const* d_in, const int* in_sizes, int n_in,
                              void* d_out, int out_size, void* d_ws, size_t ws_size,
                              hipStream_t stream)
{
    const float* x  = (const float*)d_in[0];
    const float* Wq = (const float*)d_in[1];
    const float* bq = (const float*)d_in[2];
    const float* Wk = (const float*)d_in[3];
    const float* bk = (const float*)d_in[4];
    const float* Wv = (const float*)d_in[5];
    const float* bv = (const float*)d_in[6];
    const float* pb = (const float*)d_in[7];
    float* out = (float*)d_out;

    char* ws = (char*)d_ws;
    unsigned short* eb  = (unsigned short*)(ws);                          // 2 MiB
    unsigned short* Wb  = (unsigned short*)(ws + ((size_t)2   << 20));    // 1.5 MiB
    unsigned short* xb  = (unsigned short*)(ws + ((size_t)4   << 20));    // 64 MiB
    unsigned short* s   = (unsigned short*)(ws + ((size_t)68  << 20));    // 64 MiB
    unsigned short* Z   = (unsigned short*)(ws + ((size_t)132 << 20));    // 128 MiB

    k_eb <<<1024, 256, 0, stream>>>(pb, eb);
    k_cvt<<<16384, 256, 0, stream>>>(x,  xb);
    k_cvt<<<128,   256, 0, stream>>>(Wq, Wb);
    k_cvt_kv<<<128, 256, 0, stream>>>(Wk, Wb, 0);
    k_cvt_kv<<<128, 256, 0, stream>>>(Wv, Wb, 64);
    k_qkv<<<1536, 512, 131072, stream>>>(xb, Wb, bq, bk, bv, s, Z);
    k_aft<<<256, 512, 131072, stream>>>(eb, Z, s, out);
}